// Round 11
// baseline (220.383 us; speedup 1.0000x reference)
//
#include <hip/hip_runtime.h>
#include <hip/hip_bf16.h>

// Problem constants
#define B_TOT  4096
#define M_TOT  65536
#define D_V    64
#define KD     96            // 64 (keys) + 32 (0.5*contexts); Q side pre-scaled by log2e
#define BQ     128           // q rows per block (4 waves x 32)
#define BN     64            // keys per inner tile
#define NQT    (B_TOT / BQ)  // 32
#define SHIFT2 23.0f         // fixed softmax shift in exp2 domain

using short8   = __attribute__((ext_vector_type(8))) short;
using floatx4  = __attribute__((ext_vector_type(4))) float;
using int4v    = __attribute__((ext_vector_type(4))) int;

static __device__ __forceinline__ unsigned short f2bf(float f) {
  return __builtin_bit_cast(unsigned short, __float2bfloat16(f));
}

// truncation pack: two f32 -> one dword of bf16 (lo=a, hi=b). ~2 VALU ops.
// Bias cancels: l is computed (ones-MFMA) from the same truncated P.
static __device__ __forceinline__ int pack_bf16(float a, float b) {
  unsigned ua = __builtin_bit_cast(unsigned, a);
  unsigned ub = __builtin_bit_cast(unsigned, b);
  return (int)((ua >> 16) | (ub & 0xFFFF0000u));
}

// RNE pack for the epilogue (runs once; accuracy over speed)
static __device__ __forceinline__ int pack_bf16_rne(float a, float b) {
  return (int)((unsigned)f2bf(a) | ((unsigned)f2bf(b) << 16));
}

static __device__ __forceinline__ floatx4 mfma16(short8 a, short8 b, floatx4 c) {
  return __builtin_amdgcn_mfma_f32_16x16x32_bf16(a, b, c, 0, 0, 0);
}

#define LOG2E 1.4426950408889634f

// ---- fused prep kernel ------------------------------------------------------
// blocks [0,1024): kc2   [1024,2048): vt2   [2048,3584): qc   [3584,3840): bias

#define NB_K 1024
#define NB_V 1024
#define NB_Q 1536
#define NB_B 256

__global__ __launch_bounds__(256) void
prep_all(const float* __restrict__ q, const float* __restrict__ ctx,
         const float* __restrict__ keys, const float* __restrict__ ctxs,
         const float* __restrict__ vals, const float* __restrict__ ts,
         const int* __restrict__ used,
         unsigned short* __restrict__ qc, unsigned short* __restrict__ kc2,
         unsigned short* __restrict__ vt2, float* __restrict__ bias)
{
  __shared__ float sbuf[64 * 65 + 64 * 33];
  const int bid = blockIdx.x;
  const int t = threadIdx.x;

  if (bid < NB_K) {
    // K+context in MFMA fragment-linear order (A-operand of S^T = K*Q^T):
    // kc2[g][c][lane][8], c = nt*3+s; elem = Kc[m=g*64+nt*16+(lane&15)][kk=s*32+(lane>>4)*8+j]
    float* lk = sbuf;               // [64][65]
    float* lx = sbuf + 64 * 65;     // [64][33]
    const int g = bid;
    const float* kb = keys + (size_t)g * 64 * 64;
    const float* xb = ctxs + (size_t)g * 64 * 32;
#pragma unroll
    for (int i = 0; i < 16; ++i) {
      int idx = i * 256 + t;
      lk[(idx >> 6) * 65 + (idx & 63)] = kb[idx];
    }
#pragma unroll
    for (int i = 0; i < 8; ++i) {
      int idx = i * 256 + t;
      lx[(idx >> 5) * 33 + (idx & 31)] = xb[idx];
    }
    __syncthreads();
    unsigned short* outp = kc2 + (size_t)g * 6144;
#pragma unroll
    for (int p = 0; p < 3; ++p) {
      int o = p * 2048 + t * 8;
      int c = o >> 9;
      int lane = (o >> 3) & 63;
      int lqq = lane >> 4, lcc = lane & 15;
      int nt = c / 3, s = c - nt * 3;
      int ml = nt * 16 + lcc;
      short8 v;
#pragma unroll
      for (int j = 0; j < 8; ++j) {
        int kk = s * 32 + lqq * 8 + j;
        float f = (kk < 64) ? lk[ml * 65 + kk] : lx[ml * 33 + (kk - 64)];
        v[j] = (short)f2bf(f);
      }
      *reinterpret_cast<short8*>(outp + o) = v;
    }
  } else if (bid < NB_K + NB_V) {
    // V fragment-linear (B-operand of P*V), with the key-permutation baked in
    // so the packed exp2 output IS the PV A-fragment:
    //   pi(lq*8+j) = (j<4) ? lq*4+j : 16 + lq*4 + (j-4)
    // vt2[g][c2][lane][8], c2 = h*4+nd;
    // elem = V[m = g*64 + h*32 + pi(lq*8+j)][d = nd*16+(lane&15)]
    float* lv = sbuf;               // [64][65]
    const int g = bid - NB_K;
    const float* vb = vals + (size_t)g * 64 * 64;
#pragma unroll
    for (int i = 0; i < 16; ++i) {
      int idx = i * 256 + t;
      lv[(idx >> 6) * 65 + (idx & 63)] = vb[idx];
    }
    __syncthreads();
    unsigned short* outp = vt2 + (size_t)g * 4096;
#pragma unroll
    for (int p = 0; p < 2; ++p) {
      int o = p * 2048 + t * 8;
      int c2 = o >> 9;
      int lane = (o >> 3) & 63;
      int lqq = lane >> 4, lcc = lane & 15;
      int h = c2 >> 2, nd = c2 & 3;
      short8 w;
#pragma unroll
      for (int j = 0; j < 8; ++j) {
        int mloc = h * 32 + ((j < 4) ? (lqq * 4 + j) : (16 + lqq * 4 + (j - 4)));
        w[j] = (short)f2bf(lv[mloc * 65 + nd * 16 + lcc]);
      }
      *reinterpret_cast<short8*>(outp + o) = w;
    }
  } else if (bid < NB_K + NB_V + NB_Q) {
    int tt = (bid - NB_K - NB_V) * 256 + t;     // 4096*96
    int b = tt / KD, j = tt % KD;
    float v = (j < 64) ? q[b * 64 + j] : 0.5f * ctx[b * 32 + (j - 64)];
    qc[tt] = f2bf(v * LOG2E);
  } else {
    int m = (bid - NB_K - NB_V - NB_Q) * 256 + t;
    bias[m] = used[m] ? (LOG2E * 0.3f * __expf(-0.1f * (1.0f - ts[m])) - SHIFT2) : -1e9f;
  }
}

// ---- flash attention main kernel -------------------------------------------
// grid (NQT, NC); block 256 = 4 waves; each wave owns 32 q rows (2 B-frags).
// K/V staged per block-iter into double-buffered LDS (global_load_lds w=16).
// nt-level software pipeline: V-frags of iter it are read into REGISTERS at
// the end of body(it); PV(it-1) MFMAs are interleaved inside body(it)'s
// QK/exp2 stream (no LDS dependence), dissolving the phase convoy.
// S^T = K*Q^T; packed exp2 output IS the PV A-fragment (V rows pre-permuted).
// Row sums via ones-MFMA on the truncated P (bias cancels in the ratio).
// Partial O written as packed bf16 in lane-linear order (4 dwordx4 / wave).

template<int NC>
__global__ __launch_bounds__(256, 3) void
flash_kernel(const unsigned short* __restrict__ qc,
             const unsigned short* __restrict__ kc2,
             const unsigned short* __restrict__ vt2,
             const float* __restrict__ bias,
             int4v* __restrict__ opart, float* __restrict__ lpart)
{
  constexpr int MC  = M_TOT / NC;      // keys per block
  constexpr int NIT = MC / BN;         // >= 2
  __shared__ __align__(16) unsigned short lds_kv[2 * 10240];  // 40960 B
  const int qt    = blockIdx.x;
  const int chunk = blockIdx.y;
  const int tid   = threadIdx.x;
  const int w     = tid >> 6;
  const int lane  = tid & 63;
  const int lq    = lane >> 4;
  const int lc    = lane & 15;

  floatx4 zero; zero[0] = 0.f; zero[1] = 0.f; zero[2] = 0.f; zero[3] = 0.f;

  // Q fragments (B-operand): q-rows qt*128 + w*32 + a*16 + lc
  short8 qf[2][3];
#pragma unroll
  for (int a = 0; a < 2; ++a) {
    const unsigned short* qrp = qc + (size_t)(qt * BQ + w * 32 + a * 16 + lc) * KD + lq * 8;
    qf[a][0] = *reinterpret_cast<const short8*>(qrp);
    qf[a][1] = *reinterpret_cast<const short8*>(qrp + 32);
    qf[a][2] = *reinterpret_cast<const short8*>(qrp + 64);
  }

  short8 ones;
#pragma unroll
  for (int i = 0; i < 8; ++i) ones[i] = (short)0x3F80;  // bf16 1.0

  const int g0 = chunk * (MC / 64);
  const float* bptr = bias + chunk * MC + lq * 4;

  // cooperative stage of one 64-key group: 20 x 1KB pieces, 5 per wave
  auto stage = [&](int it, int buf) {
    const unsigned short* kg = kc2 + (size_t)(g0 + it) * 6144;
    const unsigned short* vg = vt2 + (size_t)(g0 + it) * 4096;
    unsigned short* lb = lds_kv + buf * 10240;
#pragma unroll
    for (int j5 = 0; j5 < 5; ++j5) {
      int j = w + j5 * 4;
      const unsigned short* src = (j < 12) ? (kg + j * 512) : (vg + (j - 12) * 512);
      __builtin_amdgcn_global_load_lds(
          (const __attribute__((address_space(1))) void*)(src + lane * 8),
          (__attribute__((address_space(3))) void*)(lb + j * 512),
          16, 0, 0);
    }
  };

  floatx4 o[2][4];
#pragma unroll
  for (int a = 0; a < 2; ++a)
#pragma unroll
    for (int nd = 0; nd < 4; ++nd) o[a][nd] = zero;
  floatx4 lacc[2] = {zero, zero};
  int4v pk[2][2];
  short8 vf[8];

  // V-frags of buffer lb -> registers (PV then has no LDS dependence)
  auto vload = [&](const unsigned short* lb) {
#pragma unroll
    for (int c = 0; c < 8; ++c)
      vf[c] = *reinterpret_cast<const short8*>(lb + 6144 + c * 512 + lane * 8);
  };

  // QK(it) + exp2/pack; PV(it-1) interleaved per-nt when do_pv
  auto body = [&](const unsigned short* lb, const float* bp, bool do_pv) {
    int4v npk[2][2];
#pragma unroll
    for (int nt = 0; nt < 4; ++nt) {
      short8 k0 = *reinterpret_cast<const short8*>(lb + (nt * 3 + 0) * 512 + lane * 8);
      short8 k1 = *reinterpret_cast<const short8*>(lb + (nt * 3 + 1) * 512 + lane * 8);
      short8 k2 = *reinterpret_cast<const short8*>(lb + (nt * 3 + 2) * 512 + lane * 8);
      floatx4 b4 = *reinterpret_cast<const floatx4*>(bp + nt * 16);
#pragma unroll
      for (int a = 0; a < 2; ++a) {
        floatx4 acc = zero;
        acc = mfma16(k0, qf[a][0], acc);
        acc = mfma16(k1, qf[a][1], acc);
        acc = mfma16(k2, qf[a][2], acc);
        float p0 = __builtin_amdgcn_exp2f(acc[0] + b4[0]);
        float p1 = __builtin_amdgcn_exp2f(acc[1] + b4[1]);
        float p2 = __builtin_amdgcn_exp2f(acc[2] + b4[2]);
        float p3 = __builtin_amdgcn_exp2f(acc[3] + b4[3]);
        npk[a][nt >> 1][(nt & 1) * 2]     = pack_bf16(p0, p1);
        npk[a][nt >> 1][(nt & 1) * 2 + 1] = pack_bf16(p2, p3);
      }
      if (do_pv) {
        const int nd = nt;   // PV for previous iter, from registers
#pragma unroll
        for (int a = 0; a < 2; ++a) {
          o[a][nd] = mfma16(__builtin_bit_cast(short8, pk[a][0]), vf[nd],     o[a][nd]);
          o[a][nd] = mfma16(__builtin_bit_cast(short8, pk[a][1]), vf[4 + nd], o[a][nd]);
        }
      }
    }
#pragma unroll
    for (int a = 0; a < 2; ++a) {
      lacc[a] = mfma16(__builtin_bit_cast(short8, npk[a][0]), ones, lacc[a]);
      lacc[a] = mfma16(__builtin_bit_cast(short8, npk[a][1]), ones, lacc[a]);
      pk[a][0] = npk[a][0];
      pk[a][1] = npk[a][1];
    }
  };

  // prologue
  stage(0, 0);
  __syncthreads();                  // stage(0) landed
  stage(1, 1);
  body(lds_kv, bptr, false);
  vload(lds_kv);
  bptr += BN;

#pragma unroll 1
  for (int it = 1; it < NIT; ++it) {
    __syncthreads();               // stage(it) landed; buf(it-1) reads all done
    if (it + 1 < NIT) stage(it + 1, (it + 1) & 1);
    const unsigned short* lb = lds_kv + (it & 1) * 10240;
    body(lb, bptr, true);
    vload(lb);
    bptr += BN;
  }
  // final PV for iter NIT-1
#pragma unroll
  for (int nd = 0; nd < 4; ++nd)
#pragma unroll
    for (int a = 0; a < 2; ++a) {
      o[a][nd] = mfma16(__builtin_bit_cast(short8, pk[a][0]), vf[nd],     o[a][nd]);
      o[a][nd] = mfma16(__builtin_bit_cast(short8, pk[a][1]), vf[4 + nd], o[a][nd]);
    }

  // epilogue: packed-bf16 lane-linear partial O, fp32 l
  const int pb = qt * NC + chunk;
#pragma unroll
  for (int a = 0; a < 2; ++a) {
#pragma unroll
    for (int ndp = 0; ndp < 2; ++ndp) {
      int4v v;
      v[0] = pack_bf16_rne(o[a][ndp * 2 + 0][0], o[a][ndp * 2 + 0][1]);
      v[1] = pack_bf16_rne(o[a][ndp * 2 + 0][2], o[a][ndp * 2 + 0][3]);
      v[2] = pack_bf16_rne(o[a][ndp * 2 + 1][0], o[a][ndp * 2 + 1][1]);
      v[3] = pack_bf16_rne(o[a][ndp * 2 + 1][2], o[a][ndp * 2 + 1][3]);
      opart[(((size_t)pb * 4 + w) * 2 + a) * 128 + ndp * 64 + lane] = v;
    }
    // lacc C-layout: lane (lq,lc) reg r holds l[q-row = lq*4+r] (same across lc)
    if (lc == 0) {
      float* lp = lpart + (size_t)pb * BQ + w * 32 + a * 16 + lq * 4;
#pragma unroll
      for (int r = 0; r < 4; ++r) lp[r] = lacc[a][r];
    }
  }
}

// ---- final reduction (reads packed bf16 int4, coalesced) --------------------

template<int NC>
__global__ void reduce_out(const int4v* __restrict__ opart, const float* __restrict__ lpart,
                           float* __restrict__ out) {
  int t = blockIdx.x * 256 + threadIdx.x;   // 32768 threads: qt*4w*2a*2ndp*64lane
  int lane = t & 63;
  int ndp  = (t >> 6) & 1;
  int a    = (t >> 7) & 1;
  int w    = (t >> 8) & 3;
  int qt   = t >> 10;
  int lq = lane >> 4, lc = lane & 15;

  float s[8];
#pragma unroll
  for (int k = 0; k < 8; ++k) s[k] = 0.f;
  float l4[4] = {0.f, 0.f, 0.f, 0.f};

#pragma unroll 4
  for (int c = 0; c < NC; ++c) {
    int pb = qt * NC + c;
    int4v v = opart[(((size_t)pb * 4 + w) * 2 + a) * 128 + ndp * 64 + lane];
#pragma unroll
    for (int k = 0; k < 4; ++k) {
      unsigned dw = (unsigned)v[k];
      s[k * 2 + 0] += __builtin_bit_cast(float, dw << 16);
      s[k * 2 + 1] += __builtin_bit_cast(float, dw & 0xFFFF0000u);
    }
    const float* lp = lpart + (size_t)pb * BQ + w * 32 + a * 16 + lq * 4;
#pragma unroll
    for (int r = 0; r < 4; ++r) l4[r] += lp[r];
  }

  const int qbase = qt * BQ + w * 32 + a * 16 + lq * 4;
  const int nd0 = ndp * 2;
#pragma unroll
  for (int half = 0; half < 2; ++half) {
    int d = (nd0 + half) * 16 + lc;
#pragma unroll
    for (int r = 0; r < 4; ++r)
      out[(size_t)(qbase + r) * D_V + d] = s[half * 4 + r] / l4[r];
  }
}

// ---- launcher ---------------------------------------------------------------

template<int NC>
static void launch_all(const float* query, const float* context, const float* keys,
                       const float* values, const float* contexts, const float* ts,
                       const int* used, float* out, char* ws, hipStream_t stream) {
  unsigned short* qc  = (unsigned short*)ws;  ws += (size_t)B_TOT * KD * 2;
  unsigned short* kc2 = (unsigned short*)ws;  ws += (size_t)M_TOT * KD * 2;
  unsigned short* vt2 = (unsigned short*)ws;  ws += (size_t)D_V * M_TOT * 2;
  float* bias  = (float*)ws;                  ws += (size_t)M_TOT * 4;
  int4v* opart = (int4v*)ws;                  ws += (size_t)NC * B_TOT * D_V * 2;  // bf16
  float* lpart = (float*)ws;

  prep_all<<<NB_K + NB_V + NB_Q + NB_B, 256, 0, stream>>>(
      query, context, keys, contexts, values, ts, used, qc, kc2, vt2, bias);

  dim3 grid(NQT, NC);
  flash_kernel<NC><<<grid, 256, 0, stream>>>(qc, kc2, vt2, bias, opart, lpart);

  reduce_out<NC><<<128, 256, 0, stream>>>(opart, lpart, out);
}

extern "C" void kernel_launch(void* const* d_in, const int* in_sizes, int n_in,
                              void* d_out, int out_size, void* d_ws, size_t ws_size,
                              hipStream_t stream) {
  const float* query    = (const float*)d_in[0];
  const float* context  = (const float*)d_in[1];
  const float* keys     = (const float*)d_in[2];
  const float* values   = (const float*)d_in[3];
  const float* contexts = (const float*)d_in[4];
  const float* ts       = (const float*)d_in[5];
  const int*   used     = (const int*)d_in[6];
  float* out = (float*)d_out;
  char* ws = (char*)d_ws;

  const size_t fixed = (size_t)B_TOT * KD * 2 + (size_t)M_TOT * KD * 2 +
                       (size_t)D_V * M_TOT * 2 + (size_t)M_TOT * 4;
  const size_t need32 = fixed + 32ull * ((size_t)B_TOT * D_V * 2 + (size_t)B_TOT * 4);

  if (ws_size >= need32)
    launch_all<32>(query, context, keys, values, contexts, ts, used, out, ws, stream);
  else
    launch_all<16>(query, context, keys, values, contexts, ts, used, out, ws, stream);
}

// Round 12
// 204.621 us; speedup vs baseline: 1.0770x; 1.0770x over previous
//
#include <hip/hip_runtime.h>
#include <hip/hip_bf16.h>

// Problem constants
#define B_TOT  4096
#define M_TOT  65536
#define D_V    64
#define KD     96            // 64 (keys) + 32 (0.5*contexts); Q side pre-scaled by log2e
#define BQ     128           // q rows per block (4 waves x 32)
#define BN     64            // keys per inner tile
#define NQT    (B_TOT / BQ)  // 32
#define SHIFT2 23.0f         // fixed softmax shift in exp2 domain

using short8   = __attribute__((ext_vector_type(8))) short;
using floatx4  = __attribute__((ext_vector_type(4))) float;
using int4v    = __attribute__((ext_vector_type(4))) int;

static __device__ __forceinline__ unsigned short f2bf(float f) {
  return __builtin_bit_cast(unsigned short, __float2bfloat16(f));
}

// truncation pack: two f32 -> one dword of bf16 (lo=a, hi=b). ~2 VALU ops.
// Bias cancels: l is computed (ones-MFMA) from the same truncated P.
static __device__ __forceinline__ int pack_bf16(float a, float b) {
  unsigned ua = __builtin_bit_cast(unsigned, a);
  unsigned ub = __builtin_bit_cast(unsigned, b);
  return (int)((ua >> 16) | (ub & 0xFFFF0000u));
}

// RNE pack for the epilogue (runs once; accuracy over speed)
static __device__ __forceinline__ int pack_bf16_rne(float a, float b) {
  return (int)((unsigned)f2bf(a) | ((unsigned)f2bf(b) << 16));
}

static __device__ __forceinline__ floatx4 mfma16(short8 a, short8 b, floatx4 c) {
  return __builtin_amdgcn_mfma_f32_16x16x32_bf16(a, b, c, 0, 0, 0);
}

#define LOG2E 1.4426950408889634f

// ---- fused prep kernel ------------------------------------------------------
// blocks [0,1024): kc2 (pure gather, no LDS)   [1024,2048): vt2
// [2048,3584): qc   [3584,3840): bias

#define NB_K 1024
#define NB_V 1024
#define NB_Q 1536
#define NB_B 256

__global__ __launch_bounds__(256) void
prep_all(const float* __restrict__ q, const float* __restrict__ ctx,
         const float* __restrict__ keys, const float* __restrict__ ctxs,
         const float* __restrict__ vals, const float* __restrict__ ts,
         const int* __restrict__ used,
         unsigned short* __restrict__ qc, unsigned short* __restrict__ kc2,
         unsigned short* __restrict__ vt2, float* __restrict__ bias)
{
  __shared__ float lv[64 * 65];
  const int bid = blockIdx.x;
  const int t = threadIdx.x;

  if (bid < NB_K) {
    // K+context in MFMA fragment-linear order (A-operand of S^T = K*Q^T):
    // kc2[g][c][lane][8], c = nt*3+s; elem = Kc[m=g*64+nt*16+(lane&15)][kk=s*32+(lane>>4)*8+j]
    // KEY INSIGHT: each 16B output chunk is a CONTIGUOUS 8-float source run ->
    // pure gather, no LDS, no barrier; every source byte read exactly once.
    const int g = bid;
    const float* kb = keys + (size_t)g * 64 * 64;
    const float* xb = ctxs + (size_t)g * 64 * 32;
    unsigned short* outp = kc2 + (size_t)g * 6144;
#pragma unroll
    for (int p = 0; p < 3; ++p) {
      int o = p * 2048 + t * 8;
      int c = o >> 9;                  // wave-uniform
      int lane = (o >> 3) & 63;
      int lq = lane >> 4, lc = lane & 15;
      int nt = c / 3, s = c - nt * 3;
      int m = nt * 16 + lc;
      const float* src = (s < 2) ? (kb + m * 64 + s * 32 + lq * 8)
                                 : (xb + m * 32 + lq * 8);
      floatx4 f0 = *reinterpret_cast<const floatx4*>(src);
      floatx4 f1 = *reinterpret_cast<const floatx4*>(src + 4);
      short8 v;
#pragma unroll
      for (int j = 0; j < 4; ++j) {
        v[j]     = (short)f2bf(f0[j]);
        v[4 + j] = (short)f2bf(f1[j]);
      }
      *reinterpret_cast<short8*>(outp + o) = v;
    }
  } else if (bid < NB_K + NB_V) {
    // V fragment-linear (B-operand of P*V), with the key-permutation baked in
    // so the packed exp2 output IS the PV A-fragment:
    //   pi(lq*8+j) = (j<4) ? lq*4+j : 16 + lq*4 + (j-4)
    // vt2[g][c2][lane][8], c2 = h*4+nd;
    // elem = V[m = g*64 + h*32 + pi(lq*8+j)][d = nd*16+(lane&15)]
    const int g = bid - NB_K;
    const float* vb = vals + (size_t)g * 64 * 64;
    // stage V tile via float4 loads (true transpose: d fixed, m varies)
#pragma unroll
    for (int i = 0; i < 4; ++i) {
      int idx4 = i * 256 + t;              // 1024 float4s = 64x64 floats
      floatx4 f = reinterpret_cast<const floatx4*>(vb)[idx4];
      int r = idx4 >> 4, c0 = (idx4 & 15) * 4;
#pragma unroll
      for (int k = 0; k < 4; ++k) lv[r * 65 + c0 + k] = f[k];
    }
    __syncthreads();
    unsigned short* outp = vt2 + (size_t)g * 4096;
#pragma unroll
    for (int p = 0; p < 2; ++p) {
      int o = p * 2048 + t * 8;
      int c2 = o >> 9;
      int lane = (o >> 3) & 63;
      int lqq = lane >> 4, lcc = lane & 15;
      int h = c2 >> 2, nd = c2 & 3;
      short8 w;
#pragma unroll
      for (int j = 0; j < 8; ++j) {
        int mloc = h * 32 + ((j < 4) ? (lqq * 4 + j) : (16 + lqq * 4 + (j - 4)));
        w[j] = (short)f2bf(lv[mloc * 65 + nd * 16 + lcc]);
      }
      *reinterpret_cast<short8*>(outp + o) = w;
    }
  } else if (bid < NB_K + NB_V + NB_Q) {
    int tt = (bid - NB_K - NB_V) * 256 + t;     // 4096*96
    int b = tt / KD, j = tt % KD;
    float v = (j < 64) ? q[b * 64 + j] : 0.5f * ctx[b * 32 + (j - 64)];
    qc[tt] = f2bf(v * LOG2E);
  } else {
    int m = (bid - NB_K - NB_V - NB_Q) * 256 + t;
    bias[m] = used[m] ? (LOG2E * 0.3f * __expf(-0.1f * (1.0f - ts[m])) - SHIFT2) : -1e9f;
  }
}

// ---- flash attention main kernel -------------------------------------------
// grid (NQT, NC); block 256 = 4 waves; each wave owns 32 q rows (2 B-frags).
// K/V staged per block-iter into double-buffered LDS (global_load_lds w=16).
// Software-pipelined (R10 structure): PV(it-1) runs BEFORE the barrier of
// iter it, from the still-valid other LDS buffer. S^T = K*Q^T; packed exp2
// output IS the PV A-fragment (V rows pre-permuted). Row sums via ones-MFMA.
// Partial O written as packed bf16 lane-linear (4 dwordx4 per wave).

template<int NC>
__global__ __launch_bounds__(256, 4) void
flash_kernel(const unsigned short* __restrict__ qc,
             const unsigned short* __restrict__ kc2,
             const unsigned short* __restrict__ vt2,
             const float* __restrict__ bias,
             int4v* __restrict__ opart, float* __restrict__ lpart)
{
  constexpr int MC  = M_TOT / NC;      // keys per block
  constexpr int NIT = MC / BN;         // >= 2
  __shared__ __align__(16) unsigned short lds_kv[2 * 10240];  // 40960 B
  const int qt    = blockIdx.x;
  const int chunk = blockIdx.y;
  const int tid   = threadIdx.x;
  const int w     = tid >> 6;
  const int lane  = tid & 63;
  const int lq    = lane >> 4;
  const int lc    = lane & 15;

  floatx4 zero; zero[0] = 0.f; zero[1] = 0.f; zero[2] = 0.f; zero[3] = 0.f;

  // Q fragments (B-operand): q-rows qt*128 + w*32 + a*16 + lc
  short8 qf[2][3];
#pragma unroll
  for (int a = 0; a < 2; ++a) {
    const unsigned short* qrp = qc + (size_t)(qt * BQ + w * 32 + a * 16 + lc) * KD + lq * 8;
    qf[a][0] = *reinterpret_cast<const short8*>(qrp);
    qf[a][1] = *reinterpret_cast<const short8*>(qrp + 32);
    qf[a][2] = *reinterpret_cast<const short8*>(qrp + 64);
  }

  short8 ones;
#pragma unroll
  for (int i = 0; i < 8; ++i) ones[i] = (short)0x3F80;  // bf16 1.0

  const int g0 = chunk * (MC / 64);
  const float* bptr = bias + chunk * MC + lq * 4;

  // cooperative stage of one 64-key group: 20 x 1KB pieces, 5 per wave
  auto stage = [&](int it, int buf) {
    const unsigned short* kg = kc2 + (size_t)(g0 + it) * 6144;
    const unsigned short* vg = vt2 + (size_t)(g0 + it) * 4096;
    unsigned short* lb = lds_kv + buf * 10240;
#pragma unroll
    for (int j5 = 0; j5 < 5; ++j5) {
      int j = w + j5 * 4;
      const unsigned short* src = (j < 12) ? (kg + j * 512) : (vg + (j - 12) * 512);
      __builtin_amdgcn_global_load_lds(
          (const __attribute__((address_space(1))) void*)(src + lane * 8),
          (__attribute__((address_space(3))) void*)(lb + j * 512),
          16, 0, 0);
    }
  };

  floatx4 o[2][4];
#pragma unroll
  for (int a = 0; a < 2; ++a)
#pragma unroll
    for (int nd = 0; nd < 4; ++nd) o[a][nd] = zero;
  floatx4 lacc[2] = {zero, zero};
  int4v pk[2][2];

  // QK + exp2 + pack phase (fills pk; accumulates row sums via ones-MFMA)
  auto qk_phase = [&](const unsigned short* lb, const float* bp) {
#pragma unroll
    for (int nt = 0; nt < 4; ++nt) {
      short8 k0 = *reinterpret_cast<const short8*>(lb + (nt * 3 + 0) * 512 + lane * 8);
      short8 k1 = *reinterpret_cast<const short8*>(lb + (nt * 3 + 1) * 512 + lane * 8);
      short8 k2 = *reinterpret_cast<const short8*>(lb + (nt * 3 + 2) * 512 + lane * 8);
      floatx4 b4 = *reinterpret_cast<const floatx4*>(bp + nt * 16);
#pragma unroll
      for (int a = 0; a < 2; ++a) {
        floatx4 acc = zero;
        acc = mfma16(k0, qf[a][0], acc);
        acc = mfma16(k1, qf[a][1], acc);
        acc = mfma16(k2, qf[a][2], acc);
        float p0 = __builtin_amdgcn_exp2f(acc[0] + b4[0]);
        float p1 = __builtin_amdgcn_exp2f(acc[1] + b4[1]);
        float p2 = __builtin_amdgcn_exp2f(acc[2] + b4[2]);
        float p3 = __builtin_amdgcn_exp2f(acc[3] + b4[3]);
        pk[a][nt >> 1][(nt & 1) * 2]     = pack_bf16(p0, p1);
        pk[a][nt >> 1][(nt & 1) * 2 + 1] = pack_bf16(p2, p3);
      }
    }
#pragma unroll
    for (int a = 0; a < 2; ++a) {
      lacc[a] = mfma16(__builtin_bit_cast(short8, pk[a][0]), ones, lacc[a]);
      lacc[a] = mfma16(__builtin_bit_cast(short8, pk[a][1]), ones, lacc[a]);
    }
  };

  // PV phase for the pk currently in registers, V frags from given buffer
  auto pv_phase = [&](const unsigned short* lb) {
#pragma unroll
    for (int nd = 0; nd < 4; ++nd) {
      short8 v0 = *reinterpret_cast<const short8*>(lb + 6144 + nd * 512 + lane * 8);
      short8 v1 = *reinterpret_cast<const short8*>(lb + 6144 + (4 + nd) * 512 + lane * 8);
#pragma unroll
      for (int a = 0; a < 2; ++a) {
        o[a][nd] = mfma16(__builtin_bit_cast(short8, pk[a][0]), v0, o[a][nd]);
        o[a][nd] = mfma16(__builtin_bit_cast(short8, pk[a][1]), v1, o[a][nd]);
      }
    }
  };

  // prologue
  stage(0, 0);
  __syncthreads();                  // stage(0) landed
  stage(1, 1);
  qk_phase(lds_kv, bptr);
  bptr += BN;

#pragma unroll 1
  for (int it = 1; it < NIT; ++it) {
    // PV for iter it-1: buffer (it-1)&1 still valid (stage(it+1) not yet issued)
    pv_phase(lds_kv + ((it - 1) & 1) * 10240);
    __syncthreads();               // drains PV ds_reads + stage(it) vmcnt
    if (it + 1 < NIT) stage(it + 1, (it + 1) & 1);
    qk_phase(lds_kv + (it & 1) * 10240, bptr);
    bptr += BN;
  }
  pv_phase(lds_kv + ((NIT - 1) & 1) * 10240);

  // epilogue: packed-bf16 lane-linear partial O, fp32 l
  const int pb = qt * NC + chunk;
#pragma unroll
  for (int a = 0; a < 2; ++a) {
#pragma unroll
    for (int ndp = 0; ndp < 2; ++ndp) {
      int4v v;
      v[0] = pack_bf16_rne(o[a][ndp * 2 + 0][0], o[a][ndp * 2 + 0][1]);
      v[1] = pack_bf16_rne(o[a][ndp * 2 + 0][2], o[a][ndp * 2 + 0][3]);
      v[2] = pack_bf16_rne(o[a][ndp * 2 + 1][0], o[a][ndp * 2 + 1][1]);
      v[3] = pack_bf16_rne(o[a][ndp * 2 + 1][2], o[a][ndp * 2 + 1][3]);
      opart[(((size_t)pb * 4 + w) * 2 + a) * 128 + ndp * 64 + lane] = v;
    }
    // lacc C-layout: lane (lq,lc) reg r holds l[q-row = lq*4+r] (same across lc)
    if (lc == 0) {
      float* lp = lpart + (size_t)pb * BQ + w * 32 + a * 16 + lq * 4;
#pragma unroll
      for (int r = 0; r < 4; ++r) lp[r] = lacc[a][r];
    }
  }
}

// ---- final reduction (reads packed bf16 int4, coalesced) --------------------

template<int NC>
__global__ void reduce_out(const int4v* __restrict__ opart, const float* __restrict__ lpart,
                           float* __restrict__ out) {
  int t = blockIdx.x * 256 + threadIdx.x;   // 32768 threads: qt*4w*2a*2ndp*64lane
  int lane = t & 63;
  int ndp  = (t >> 6) & 1;
  int a    = (t >> 7) & 1;
  int w    = (t >> 8) & 3;
  int qt   = t >> 10;
  int lq = lane >> 4, lc = lane & 15;

  float s[8];
#pragma unroll
  for (int k = 0; k < 8; ++k) s[k] = 0.f;
  float l4[4] = {0.f, 0.f, 0.f, 0.f};

#pragma unroll 4
  for (int c = 0; c < NC; ++c) {
    int pb = qt * NC + c;
    int4v v = opart[(((size_t)pb * 4 + w) * 2 + a) * 128 + ndp * 64 + lane];
#pragma unroll
    for (int k = 0; k < 4; ++k) {
      unsigned dw = (unsigned)v[k];
      s[k * 2 + 0] += __builtin_bit_cast(float, dw << 16);
      s[k * 2 + 1] += __builtin_bit_cast(float, dw & 0xFFFF0000u);
    }
    const float* lp = lpart + (size_t)pb * BQ + w * 32 + a * 16 + lq * 4;
#pragma unroll
    for (int r = 0; r < 4; ++r) l4[r] += lp[r];
  }

  const int qbase = qt * BQ + w * 32 + a * 16 + lq * 4;
  const int nd0 = ndp * 2;
#pragma unroll
  for (int half = 0; half < 2; ++half) {
    int d = (nd0 + half) * 16 + lc;
#pragma unroll
    for (int r = 0; r < 4; ++r)
      out[(size_t)(qbase + r) * D_V + d] = s[half * 4 + r] / l4[r];
  }
}

// ---- launcher ---------------------------------------------------------------

template<int NC>
static void launch_all(const float* query, const float* context, const float* keys,
                       const float* values, const float* contexts, const float* ts,
                       const int* used, float* out, char* ws, hipStream_t stream) {
  unsigned short* qc  = (unsigned short*)ws;  ws += (size_t)B_TOT * KD * 2;
  unsigned short* kc2 = (unsigned short*)ws;  ws += (size_t)M_TOT * KD * 2;
  unsigned short* vt2 = (unsigned short*)ws;  ws += (size_t)D_V * M_TOT * 2;
  float* bias  = (float*)ws;                  ws += (size_t)M_TOT * 4;
  int4v* opart = (int4v*)ws;                  ws += (size_t)NC * B_TOT * D_V * 2;  // bf16
  float* lpart = (float*)ws;

  prep_all<<<NB_K + NB_V + NB_Q + NB_B, 256, 0, stream>>>(
      query, context, keys, contexts, values, ts, used, qc, kc2, vt2, bias);

  dim3 grid(NQT, NC);
  flash_kernel<NC><<<grid, 256, 0, stream>>>(qc, kc2, vt2, bias, opart, lpart);

  reduce_out<NC><<<128, 256, 0, stream>>>(opart, lpart, out);
}

extern "C" void kernel_launch(void* const* d_in, const int* in_sizes, int n_in,
                              void* d_out, int out_size, void* d_ws, size_t ws_size,
                              hipStream_t stream) {
  const float* query    = (const float*)d_in[0];
  const float* context  = (const float*)d_in[1];
  const float* keys     = (const float*)d_in[2];
  const float* values   = (const float*)d_in[3];
  const float* contexts = (const float*)d_in[4];
  const float* ts       = (const float*)d_in[5];
  const int*   used     = (const int*)d_in[6];
  float* out = (float*)d_out;
  char* ws = (char*)d_ws;

  const size_t fixed = (size_t)B_TOT * KD * 2 + (size_t)M_TOT * KD * 2 +
                       (size_t)D_V * M_TOT * 2 + (size_t)M_TOT * 4;
  const size_t need32 = fixed + 32ull * ((size_t)B_TOT * D_V * 2 + (size_t)B_TOT * 4);

  if (ws_size >= need32)
    launch_all<32>(query, context, keys, values, contexts, ts, used, out, ws, stream);
  else
    launch_all<16>(query, context, keys, values, contexts, ts, used, out, ws, stream);
}